// Round 3
// baseline (66.672 us; speedup 1.0000x reference)
//
#include <hip/hip_runtime.h>

// Shapes fixed by the reference.
#define NB    128   // batch
#define NT    128   // LEN_T
#define NA    64    // LEN_A
#define NV    64    // LEN_V

// One block = one wave (64 lanes) per batch b. Each lane owns t = lane and
// t = lane + 64.
// Math: s_b = dot(V[b], Wv);  y[b,t] = relu( sum_a relu(T[b,t]*A[b,a]*s_b + bv)*Wa[a] + ba )
__global__ __launch_bounds__(64) void triple_interaction_kernel(
    const float* __restrict__ T,
    const float* __restrict__ A,
    const float* __restrict__ V,
    const float* __restrict__ Wv,
    const float* __restrict__ bv,
    const float* __restrict__ Wa,
    const float* __restrict__ ba,
    float* __restrict__ out)
{
    __shared__ float2 cw[NA];   // (A[b,a]*s_b, Wa[a]) interleaved -> ds_read_b64

    const int b    = blockIdx.x;
    const int lane = threadIdx.x;   // 0..63

    // --- step 1: s_b = dot(V[b], Wv); butterfly leaves the sum in ALL lanes ---
    float p = V[b * NV + lane] * Wv[lane];
    #pragma unroll
    for (int off = 32; off >= 1; off >>= 1)
        p += __shfl_xor(p, off, 64);
    const float s = p;

    // --- step 2: stage (A*s, Wa) pairs in LDS (lane a produces entry a) ---
    cw[lane] = make_float2(A[b * NA + lane] * s, Wa[lane]);
    __syncthreads();   // single wave: compiles to a trivial barrier, kept for safety

    // --- step 3: contraction over a for this lane's two t values ---
    const float bvf = bv[0];
    const float baf = ba[0];
    const float tb0 = T[b * NT + lane];
    const float tb1 = T[b * NT + 64 + lane];

    float y0 = 0.0f, y1 = 0.0f;
    #pragma unroll
    for (int a = 0; a < NA; ++a) {
        const float2 c = cw[a];                    // broadcast read, conflict-free
        float x0 = fmaxf(fmaf(tb0, c.x, bvf), 0.0f);
        float x1 = fmaxf(fmaf(tb1, c.x, bvf), 0.0f);
        y0 = fmaf(x0, c.y, y0);
        y1 = fmaf(x1, c.y, y1);
    }
    out[b * NT + lane]      = fmaxf(y0 + baf, 0.0f);
    out[b * NT + 64 + lane] = fmaxf(y1 + baf, 0.0f);
}

extern "C" void kernel_launch(void* const* d_in, const int* in_sizes, int n_in,
                              void* d_out, int out_size, void* d_ws, size_t ws_size,
                              hipStream_t stream) {
    (void)in_sizes; (void)n_in; (void)d_ws; (void)ws_size; (void)out_size;

    const float* T  = (const float*)d_in[0];
    const float* A  = (const float*)d_in[1];
    const float* V  = (const float*)d_in[2];
    const float* Wv = (const float*)d_in[3];
    const float* bv = (const float*)d_in[4];
    const float* Wa = (const float*)d_in[5];
    const float* ba = (const float*)d_in[6];
    float* out = (float*)d_out;

    triple_interaction_kernel<<<NB, 64, 0, stream>>>(T, A, V, Wv, bv, Wa, ba, out);
}